// Round 11
// baseline (140.723 us; speedup 1.0000x reference)
//
#include <hip/hip_runtime.h>
#include <hip/hip_bf16.h>

#ifndef __has_builtin
#define __has_builtin(x) 0
#endif

__device__ __forceinline__ float fast_exp2(float x) {
#if __has_builtin(__builtin_amdgcn_exp2f)
  return __builtin_amdgcn_exp2f(x);
#else
  return exp2f(x);
#endif
}
__device__ __forceinline__ float fast_rcp(float x) {
#if __has_builtin(__builtin_amdgcn_rcpf)
  return __builtin_amdgcn_rcpf(x);
#else
  return 1.0f / x;
#endif
}

constexpr int Bsz = 8, QL = 128, KL = 512, DD = 256, UU = 256;
constexpr int PR = 4;                    // rows per proj block (1280 blocks)
constexpr int DT = 8;                    // d-chunk in proj pipeline
constexpr float NEG_INF = -1e6f;
constexpr float C2 = 2.885390081777927f; // 2*log2(e): exp2(C2*x) == exp(2x)

// ---------------------------------------------------------------------------
// Kernel 1: projections, pre-scaled by C2 (R8 config: best measured ~20us).
//   qp [b][q][u]  natural;  kpT[b][u][k] transposed (scores lanes map to k).
// PR=4 -> 1280 blocks (5/CU). W traffic = 327 MB (~10us L2 floor). Dual
// double-buffer: next tile's W AND rows issued before current compute.
// Masked key blocks exit early.
// ---------------------------------------------------------------------------
__global__ __launch_bounds__(256) void proj_kernel(
    const float* __restrict__ query, const float* __restrict__ key,
    const float* __restrict__ Wq, const float* __restrict__ Wk,
    const int* __restrict__ valid_len,
    float* __restrict__ qp, float* __restrict__ kpT)
{
  const int u   = threadIdx.x;
  const int blk = blockIdx.x;
  constexpr int QBLKS = Bsz * QL / PR;   // 256
  const bool isQ = blk < QBLKS;
  const int  m0  = isQ ? blk * PR : (blk - QBLKS) * PR;

  int kb_ = 0, kk0 = 0;
  if (!isQ) {
    kb_ = m0 / KL; kk0 = m0 % KL;
    if (kk0 >= valid_len[kb_]) return;   // masked rows never read downstream
  }
  const float* __restrict__ in = isQ ? query : key;
  const float* __restrict__ W  = isQ ? Wq : Wk;
  const float* r0 = in + (size_t)m0 * DD;

  float acc[PR];
#pragma unroll
  for (int r = 0; r < PR; ++r) acc[r] = 0.f;

  float  w_c[DT], w_n[DT];
  float4 r_c[PR][2], r_n[PR][2];

#pragma unroll
  for (int j = 0; j < DT; ++j) w_c[j] = W[j * UU + u];
#pragma unroll
  for (int r = 0; r < PR; ++r) {
    r_c[r][0] = *reinterpret_cast<const float4*>(r0 + r * DD);
    r_c[r][1] = *reinterpret_cast<const float4*>(r0 + r * DD + 4);
  }

  for (int d = 0; d < DD; d += DT) {
    const int dn = (d + DT < DD) ? d + DT : 0;   // clamped dummy on last
#pragma unroll
    for (int j = 0; j < DT; ++j) w_n[j] = W[(dn + j) * UU + u];
#pragma unroll
    for (int r = 0; r < PR; ++r) {
      r_n[r][0] = *reinterpret_cast<const float4*>(r0 + r * DD + dn);
      r_n[r][1] = *reinterpret_cast<const float4*>(r0 + r * DD + dn + 4);
    }
#pragma unroll
    for (int r = 0; r < PR; ++r) {
      float a = acc[r];
      a = fmaf(r_c[r][0].x, w_c[0], a);
      a = fmaf(r_c[r][0].y, w_c[1], a);
      a = fmaf(r_c[r][0].z, w_c[2], a);
      a = fmaf(r_c[r][0].w, w_c[3], a);
      a = fmaf(r_c[r][1].x, w_c[4], a);
      a = fmaf(r_c[r][1].y, w_c[5], a);
      a = fmaf(r_c[r][1].z, w_c[6], a);
      a = fmaf(r_c[r][1].w, w_c[7], a);
      acc[r] = a;
    }
#pragma unroll
    for (int j = 0; j < DT; ++j) w_c[j] = w_n[j];
#pragma unroll
    for (int r = 0; r < PR; ++r) { r_c[r][0] = r_n[r][0]; r_c[r][1] = r_n[r][1]; }
  }

  if (isQ) {
    float* o = qp + (size_t)m0 * UU + u;
#pragma unroll
    for (int r = 0; r < PR; ++r) o[(size_t)r * UU] = acc[r] * C2;
  } else {
    float* o = kpT + ((size_t)kb_ * UU + u) * KL + kk0;
    *reinterpret_cast<float4*>(o) =
        make_float4(acc[0] * C2, acc[1] * C2, acc[2] * C2, acc[3] * C2);
  }
}

// ---------------------------------------------------------------------------
// Kernel 2: FUSED scores + masked softmax + PV, ONE q-row per block.
// 1024 blocks -> 4 blocks/CU = 16 waves/CU (~2.5 active/SIMD in scores:
// 2x R10's TLP — the counter-diagnosed limiter). launch_bounds(256,4)
// gives the allocator 128 VGPR so the prefetch buffers stay live (R10's
// VGPR=40 proved the pipeline was collapsed).
//   Scores: wave w owns k-strip [128w,128w+128); lane l owns k=128w+2l(+1);
//   per 8-u tile: STAGE-SPLIT compute — 16 independent exps into e[16],
//   then 16 rcp+fma — long same-pipe runs the scheduler can overlap.
//   kpT float2 loads + q/w2 LDS reads batched and prefetched a tile ahead.
//   Softmax: thread t owns k={2t,2t+1}; two-level (shuffle + LDS) reduce;
//   weights left unnormalized, final 1/sum scale on output.
//   PV: thread = d (256 = DD); value coalesced, 16-deep prefetch; sps
//   reads are uniform broadcasts batched per chunk.
// ---------------------------------------------------------------------------
__global__ __launch_bounds__(256, 4) void fused_attn_kernel(
    const float* __restrict__ value, const int* __restrict__ valid_len,
    const float* __restrict__ v_w, const float* __restrict__ qp,
    const float* __restrict__ kpT, float* __restrict__ out)
{
  __shared__ __align__(16) float sps[KL];    // 2 KB: scores -> exp weights
  __shared__ __align__(16) float q_s[UU];    // 1 KB
  __shared__ __align__(16) float w2_s[UU];   // 1 KB
  __shared__ float red_s[8];                 // [0..3] max, [4..7] sum

  const int t   = threadIdx.x;
  const int blk = blockIdx.x;
  const int b   = blk & 7;                   // batch fastest: mixed vlen per CU
  const int q0  = blk >> 3;                  // q row
  const int vlen = valid_len[b];
  const int w = t >> 6, l = t & 63;

  // ---- stage qp row + 2*v_w ----
  w2_s[t] = 2.0f * v_w[t];
  q_s[t]  = qp[(size_t)(b * QL + q0) * UU + t];
  __syncthreads();

  // ---- scores for wave strip ----
  const int kb = 128 * w + 2 * l;            // lane's k pair base
  float a0 = 0.f, a1 = 0.f;

  if (128 * w < vlen) {
    const float* __restrict__ kprow = kpT + (size_t)b * UU * KL + kb;

    float2 cur[8], nxt[8];
    float  qv_c[8], qv_n[8], w2_c[8], w2_n[8];

    // prologue: tile 0
#pragma unroll
    for (int j = 0; j < 8; ++j)
      cur[j] = *reinterpret_cast<const float2*>(kprow + (size_t)j * KL);
    *reinterpret_cast<float4*>(&qv_c[0]) = *reinterpret_cast<const float4*>(&q_s[0]);
    *reinterpret_cast<float4*>(&qv_c[4]) = *reinterpret_cast<const float4*>(&q_s[4]);
    *reinterpret_cast<float4*>(&w2_c[0]) = *reinterpret_cast<const float4*>(&w2_s[0]);
    *reinterpret_cast<float4*>(&w2_c[4]) = *reinterpret_cast<const float4*>(&w2_s[4]);

    for (int u0 = 0; u0 < UU; u0 += 8) {
      const int un = (u0 + 8 < UU) ? u0 + 8 : 0;   // clamped dummy on last
      // issue next tile's loads (global + LDS), stay in flight during compute
#pragma unroll
      for (int j = 0; j < 8; ++j)
        nxt[j] = *reinterpret_cast<const float2*>(kprow + (size_t)(un + j) * KL);
      *reinterpret_cast<float4*>(&qv_n[0]) =
          *reinterpret_cast<const float4*>(&q_s[un]);
      *reinterpret_cast<float4*>(&qv_n[4]) =
          *reinterpret_cast<const float4*>(&q_s[un + 4]);
      *reinterpret_cast<float4*>(&w2_n[0]) =
          *reinterpret_cast<const float4*>(&w2_s[un]);
      *reinterpret_cast<float4*>(&w2_n[4]) =
          *reinterpret_cast<const float4*>(&w2_s[un + 4]);

      // STAGE A: 16 independent exps (fills the trans pipe back-to-back)
      float e[16];
#pragma unroll
      for (int j = 0; j < 8; ++j) {
        e[2 * j]     = fast_exp2(qv_c[j] + cur[j].x);
        e[2 * j + 1] = fast_exp2(qv_c[j] + cur[j].y);
      }
      // STAGE B: 16 independent rcps + fma accumulate
#pragma unroll
      for (int j = 0; j < 8; ++j) {
        a0 = fmaf(w2_c[j], fast_rcp(1.0f + e[2 * j]),     a0);
        a1 = fmaf(w2_c[j], fast_rcp(1.0f + e[2 * j + 1]), a1);
      }
      // rotate
#pragma unroll
      for (int j = 0; j < 8; ++j) cur[j] = nxt[j];
#pragma unroll
      for (int j = 0; j < 8; ++j) { qv_c[j] = qv_n[j]; w2_c[j] = w2_n[j]; }
    }
  }
  // write scores (shift-invariant const dropped; masked -> NEG_INF; lanes
  // past vlen computed on finite ws-poison, discarded by the select)
  {
    float2 sv;
    sv.x = (kb     < vlen) ? -a0 : NEG_INF;
    sv.y = (kb + 1 < vlen) ? -a1 : NEG_INF;
    *reinterpret_cast<float2*>(&sps[kb]) = sv;
  }
  __syncthreads();

  // ---- softmax over 512 k; thread t owns k = {2t, 2t+1} ----
  const float2 sv2 = *reinterpret_cast<const float2*>(&sps[2 * t]);
  float m = fmaxf(sv2.x, sv2.y);
#pragma unroll
  for (int off = 32; off >= 1; off >>= 1) m = fmaxf(m, __shfl_xor(m, off, 64));
  if (l == 0) red_s[w] = m;
  __syncthreads();
  const float mr = fmaxf(fmaxf(red_s[0], red_s[1]), fmaxf(red_s[2], red_s[3]));
  const float e0 = __expf(sv2.x - mr);   // masked -> exp(-1e6) = 0
  const float e1 = __expf(sv2.y - mr);
  *reinterpret_cast<float2*>(&sps[2 * t]) = make_float2(e0, e1);
  float s = e0 + e1;
#pragma unroll
  for (int off = 32; off >= 1; off >>= 1) s += __shfl_xor(s, off, 64);
  if (l == 0) red_s[4 + w] = s;
  __syncthreads();
  const float inv =
      fast_rcp(red_s[4] + red_s[5] + red_s[6] + red_s[7]);  // sum >= 1

  // ---- PV: thread = d; unnormalized weights, final scale ----
  const float* __restrict__ vb = value + (size_t)b * KL * DD + t;
  float o0 = 0.f;
  const int kmax = (vlen + 15) & ~15;        // sps beyond vlen is exactly 0

  float vc[16], vn[16], p_r[16];
#pragma unroll
  for (int j = 0; j < 16; ++j) vc[j] = vb[(size_t)j * DD];
  for (int k = 0; k < kmax; k += 16) {
    const int kn = (k + 16 < kmax) ? k + 16 : 0;
#pragma unroll
    for (int i = 0; i < 4; ++i)
      *reinterpret_cast<float4*>(&p_r[4 * i]) =
          *reinterpret_cast<const float4*>(&sps[k + 4 * i]);
#pragma unroll
    for (int j = 0; j < 16; ++j) vn[j] = vb[(size_t)(kn + j) * DD];
#pragma unroll
    for (int j = 0; j < 16; ++j) o0 = fmaf(p_r[j], vc[j], o0);
#pragma unroll
    for (int j = 0; j < 16; ++j) vc[j] = vn[j];
  }
  out[(size_t)(b * QL + q0) * DD + t] = o0 * inv;
}

extern "C" void kernel_launch(void* const* d_in, const int* in_sizes, int n_in,
                              void* d_out, int out_size, void* d_ws, size_t ws_size,
                              hipStream_t stream) {
  const float* query     = (const float*)d_in[0];
  const float* key       = (const float*)d_in[1];
  const float* value     = (const float*)d_in[2];
  const int*   valid_len = (const int*)d_in[3];
  const float* Wq        = (const float*)d_in[4];
  const float* Wk        = (const float*)d_in[5];
  const float* v_w       = (const float*)d_in[6];
  float* out = (float*)d_out;

  float* qp  = (float*)d_ws;                        // B*QL*U floats (1 MB)
  float* kpT = qp + (size_t)Bsz * QL * UU;          // B*U*KL floats (4 MB)

  const int proj_blocks = (Bsz * QL + Bsz * KL) / PR;   // 1280
  proj_kernel<<<proj_blocks, 256, 0, stream>>>(query, key, Wq, Wk, valid_len,
                                               qp, kpT);

  const int fused_blocks = Bsz * QL;                    // 1024
  fused_attn_kernel<<<fused_blocks, 256, 0, stream>>>(value, valid_len, v_w,
                                                      qp, kpT, out);
}

// Round 12
// 138.549 us; speedup vs baseline: 1.0157x; 1.0157x over previous
//
#include <hip/hip_runtime.h>
#include <hip/hip_bf16.h>

#ifndef __has_builtin
#define __has_builtin(x) 0
#endif

__device__ __forceinline__ float fast_exp2(float x) {
#if __has_builtin(__builtin_amdgcn_exp2f)
  return __builtin_amdgcn_exp2f(x);
#else
  return exp2f(x);
#endif
}
__device__ __forceinline__ float fast_rcp(float x) {
#if __has_builtin(__builtin_amdgcn_rcpf)
  return __builtin_amdgcn_rcpf(x);
#else
  return 1.0f / x;
#endif
}

constexpr int Bsz = 8, QL = 128, KL = 512, DD = 256, UU = 256;
constexpr int PR = 4;                    // rows per proj block (1280 blocks)
constexpr int DT = 8;                    // d-chunk in proj pipeline
constexpr int FQB = 2;                   // q rows per fused block
constexpr float NEG_INF = -1e6f;
constexpr float C2 = 2.885390081777927f; // 2*log2(e): exp2(C2*x) == exp(2x)

// 16B-per-lane async global->LDS DMA. Side-effect intrinsic: the compiler
// CANNOT sink/collapse it the way it has collapsed every register prefetch
// in R9-R11 (VGPR stuck at 40). ldsp must be wave-uniform; lane scatter is
// implicit base + lane*16.
__device__ __forceinline__ void async_ld16(const float* g, float* ldsp) {
  __builtin_amdgcn_global_load_lds(
      (const __attribute__((address_space(1))) void*)g,
      (__attribute__((address_space(3))) void*)ldsp, 16, 0, 0);
}

// ---------------------------------------------------------------------------
// Kernel 1: projections, pre-scaled by C2 (R8 config, measured ~20us).
//   qp [b][q][u]  natural;  kpT[b][u][k] transposed (scores lanes map to k).
// PR=4 -> 1280 blocks (5/CU). Masked key blocks exit early.
// ---------------------------------------------------------------------------
__global__ __launch_bounds__(256) void proj_kernel(
    const float* __restrict__ query, const float* __restrict__ key,
    const float* __restrict__ Wq, const float* __restrict__ Wk,
    const int* __restrict__ valid_len,
    float* __restrict__ qp, float* __restrict__ kpT)
{
  const int u   = threadIdx.x;
  const int blk = blockIdx.x;
  constexpr int QBLKS = Bsz * QL / PR;   // 256
  const bool isQ = blk < QBLKS;
  const int  m0  = isQ ? blk * PR : (blk - QBLKS) * PR;

  int kb_ = 0, kk0 = 0;
  if (!isQ) {
    kb_ = m0 / KL; kk0 = m0 % KL;
    if (kk0 >= valid_len[kb_]) return;   // masked rows never read downstream
  }
  const float* __restrict__ in = isQ ? query : key;
  const float* __restrict__ W  = isQ ? Wq : Wk;
  const float* r0 = in + (size_t)m0 * DD;

  float acc[PR];
#pragma unroll
  for (int r = 0; r < PR; ++r) acc[r] = 0.f;

  float  w_c[DT], w_n[DT];
  float4 r_c[PR][2], r_n[PR][2];

#pragma unroll
  for (int j = 0; j < DT; ++j) w_c[j] = W[j * UU + u];
#pragma unroll
  for (int r = 0; r < PR; ++r) {
    r_c[r][0] = *reinterpret_cast<const float4*>(r0 + r * DD);
    r_c[r][1] = *reinterpret_cast<const float4*>(r0 + r * DD + 4);
  }

  for (int d = 0; d < DD; d += DT) {
    const int dn = (d + DT < DD) ? d + DT : 0;   // clamped dummy on last
#pragma unroll
    for (int j = 0; j < DT; ++j) w_n[j] = W[(dn + j) * UU + u];
#pragma unroll
    for (int r = 0; r < PR; ++r) {
      r_n[r][0] = *reinterpret_cast<const float4*>(r0 + r * DD + dn);
      r_n[r][1] = *reinterpret_cast<const float4*>(r0 + r * DD + dn + 4);
    }
#pragma unroll
    for (int r = 0; r < PR; ++r) {
      float a = acc[r];
      a = fmaf(r_c[r][0].x, w_c[0], a);
      a = fmaf(r_c[r][0].y, w_c[1], a);
      a = fmaf(r_c[r][0].z, w_c[2], a);
      a = fmaf(r_c[r][0].w, w_c[3], a);
      a = fmaf(r_c[r][1].x, w_c[4], a);
      a = fmaf(r_c[r][1].y, w_c[5], a);
      a = fmaf(r_c[r][1].z, w_c[6], a);
      a = fmaf(r_c[r][1].w, w_c[7], a);
      acc[r] = a;
    }
#pragma unroll
    for (int j = 0; j < DT; ++j) w_c[j] = w_n[j];
#pragma unroll
    for (int r = 0; r < PR; ++r) { r_c[r][0] = r_n[r][0]; r_c[r][1] = r_n[r][1]; }
  }

  if (isQ) {
    float* o = qp + (size_t)m0 * UU + u;
#pragma unroll
    for (int r = 0; r < PR; ++r) o[(size_t)r * UU] = acc[r] * C2;
  } else {
    float* o = kpT + ((size_t)kb_ * UU + u) * KL + kk0;
    *reinterpret_cast<float4*>(o) =
        make_float4(acc[0] * C2, acc[1] * C2, acc[2] * C2, acc[3] * C2);
  }
}

// ---------------------------------------------------------------------------
// Kernel 2: FUSED scores + masked softmax + PV for (b, 2 q-rows); 512 blocks.
// kpT is DMA-staged into an LDS double buffer with global_load_lds:
//   per 8-u tile: issue 16 x 1KB chunk DMAs for tile n+1 (4 per wave;
//   chunks whose k-half is fully masked are skipped), compute tile n from
//   LDS, then __syncthreads() — the barrier's vmcnt drain lands after
//   ~600cy of compute, so DMA latency is overlapped BY CONSTRUCTION,
//   independent of the register allocator (which collapsed every register
//   prefetch in R9-R11).
// Compute (R9's best-measured form): wave w owns k-strip [128w,128w+128);
// lane l owns k=128w+2l(+1) x 2 q rows -> 4 accs, 8 trans per u.
// Softmax + PV unchanged from R9.
// ---------------------------------------------------------------------------
__global__ __launch_bounds__(256) void fused_attn_kernel(
    const float* __restrict__ value, const int* __restrict__ valid_len,
    const float* __restrict__ v_w, const float* __restrict__ qp,
    const float* __restrict__ kpT, float* __restrict__ out)
{
  __shared__ __align__(16) float kb_s[2][8][KL];  // 32 KB dbuf, UNPADDED (DMA)
  __shared__ __align__(16) float2 sps[KL];        // 4 KB: scores -> exp weights
  __shared__ __align__(16) float2 qpq_s[UU];      // 2 KB: (q0,q1) per u
  __shared__ __align__(16) float  w2_s[UU];       // 1 KB
  __shared__ float2 red2[4];                      // max halves / sum halves

  const int t   = threadIdx.x;
  const int blk = blockIdx.x;
  const int b   = blk & 7;                   // batch fastest: mixed vlen per CU
  const int q0  = (blk >> 3) * FQB;
  const int vlen = valid_len[b];
  const int w = t >> 6, l = t & 63;

  // ---- stage qp rows (as float2 per u) + 2*v_w ----
  w2_s[t] = 2.0f * v_w[t];
  qpq_s[t] = make_float2(qp[(size_t)(b * QL + q0) * UU + t],
                         qp[(size_t)(b * QL + q0 + 1) * UU + t]);

  const float* __restrict__ kb_base = kpT + (size_t)b * UU * KL;

  // chunk c = 4w+i covers (row r = c>>1, k-half h = c&1) of the 8-row tile;
  // 64 lanes x 16B = 1 KB = half a kpT row. Skip fully-masked halves.
  auto stage = [&](int buf, int u0) {
#pragma unroll
    for (int i = 0; i < 4; ++i) {
      const int c = 4 * w + i, r = c >> 1, h = c & 1;
      if (h * 256 < vlen) {
        const float* g = kb_base + (size_t)(u0 + r) * KL + h * 256 + 4 * l;
        async_ld16(g, &kb_s[buf][r][h * 256]);
      }
    }
  };

  stage(0, 0);
  __syncthreads();                           // drains tile-0 DMA + LDS stores

  // ---- scores: compute tile n from LDS while tile n+1 DMAs ----
  const int kb = 128 * w + 2 * l;            // lane's k pair base
  float a00 = 0.f, a01 = 0.f, a10 = 0.f, a11 = 0.f;  // [row][kslot]
  const bool live = (128 * w) < vlen;

  for (int u0 = 0; u0 < UU; u0 += 8) {
    const int buf = (u0 >> 3) & 1;
    if (u0 + 8 < UU) stage(buf ^ 1, u0 + 8);
    if (live) {
#pragma unroll
      for (int j = 0; j < 8; ++j) {
        const float2 qv = qpq_s[u0 + j];     // ds_read_b64 broadcast
        const float  w2 = w2_s[u0 + j];
        const float2 kv = *reinterpret_cast<const float2*>(&kb_s[buf][j][kb]);
        const float e00 = fast_exp2(qv.x + kv.x);
        const float e01 = fast_exp2(qv.x + kv.y);
        const float e10 = fast_exp2(qv.y + kv.x);
        const float e11 = fast_exp2(qv.y + kv.y);
        a00 = fmaf(w2, fast_rcp(1.0f + e00), a00);
        a01 = fmaf(w2, fast_rcp(1.0f + e01), a01);
        a10 = fmaf(w2, fast_rcp(1.0f + e10), a10);
        a11 = fmaf(w2, fast_rcp(1.0f + e11), a11);
      }
    }
    __syncthreads();                         // waves done with buf; buf^1 DMA landed
  }

  // write scores (shift-invariant const dropped). Lanes past vlen may hold
  // garbage (unstaged LDS / unwritten kpT) — discarded by the select.
  {
    float4 sv;
    sv.x = (kb     < vlen) ? -a00 : NEG_INF;   // sps[kb].x   (row 0)
    sv.y = (kb     < vlen) ? -a10 : NEG_INF;   // sps[kb].y   (row 1)
    sv.z = (kb + 1 < vlen) ? -a01 : NEG_INF;   // sps[kb+1].x
    sv.w = (kb + 1 < vlen) ? -a11 : NEG_INF;   // sps[kb+1].y
    *reinterpret_cast<float4*>(&sps[kb]) = sv;
  }
  __syncthreads();

  // ---- softmax (both rows at once); waves 0,1 own k-halves ----
  float4 sa, sb;
  if (w < 2) {
    const int base = 256 * w + 4 * l;        // 4 consecutive k
    sa = *reinterpret_cast<const float4*>(&sps[base]);      // k, k+1
    sb = *reinterpret_cast<const float4*>(&sps[base + 2]);  // k+2, k+3
    float mx0 = fmaxf(fmaxf(sa.x, sa.z), fmaxf(sb.x, sb.z));
    float mx1 = fmaxf(fmaxf(sa.y, sa.w), fmaxf(sb.y, sb.w));
#pragma unroll
    for (int off = 32; off >= 1; off >>= 1) {
      mx0 = fmaxf(mx0, __shfl_xor(mx0, off, 64));
      mx1 = fmaxf(mx1, __shfl_xor(mx1, off, 64));
    }
    if (l == 0) red2[w] = make_float2(mx0, mx1);
  }
  __syncthreads();
  const float m0r = fmaxf(red2[0].x, red2[1].x);
  const float m1r = fmaxf(red2[0].y, red2[1].y);
  if (w < 2) {
    const int base = 256 * w + 4 * l;
    sa.x = __expf(sa.x - m0r);  sa.y = __expf(sa.y - m1r);
    sa.z = __expf(sa.z - m0r);  sa.w = __expf(sa.w - m1r);
    sb.x = __expf(sb.x - m0r);  sb.y = __expf(sb.y - m1r);
    sb.z = __expf(sb.z - m0r);  sb.w = __expf(sb.w - m1r);
    *reinterpret_cast<float4*>(&sps[base])     = sa;
    *reinterpret_cast<float4*>(&sps[base + 2]) = sb;
    float s0 = sa.x + sa.z + sb.x + sb.z;
    float s1 = sa.y + sa.w + sb.y + sb.w;
#pragma unroll
    for (int off = 32; off >= 1; off >>= 1) {
      s0 += __shfl_xor(s0, off, 64);
      s1 += __shfl_xor(s1, off, 64);
    }
    if (l == 0) red2[2 + w] = make_float2(s0, s1);
  }
  __syncthreads();
  const float inv0 = fast_rcp(red2[2].x + red2[3].x);  // sums >= 1
  const float inv1 = fast_rcp(red2[2].y + red2[3].y);

  // ---- PV: thread = d; unnormalized weights, final scale (R9 form) ----
  const float* __restrict__ vb = value + (size_t)b * KL * DD + t;
  float o0 = 0.f, o1 = 0.f;
  const int kmax = (vlen + 15) & ~15;        // sps beyond vlen is exactly 0

  float vc[16], vn[16];
#pragma unroll
  for (int j = 0; j < 16; ++j) vc[j] = vb[(size_t)j * DD];
  for (int k = 0; k < kmax; k += 16) {
    const int kn = (k + 16 < kmax) ? k + 16 : 0;
#pragma unroll
    for (int j = 0; j < 16; ++j) vn[j] = vb[(size_t)(kn + j) * DD];
#pragma unroll
    for (int j = 0; j < 16; ++j) {
      const float2 p = sps[k + j];           // broadcast
      o0 = fmaf(p.x, vc[j], o0);
      o1 = fmaf(p.y, vc[j], o1);
    }
#pragma unroll
    for (int j = 0; j < 16; ++j) vc[j] = vn[j];
  }
  out[(size_t)(b * QL + q0) * DD + t]     = o0 * inv0;
  out[(size_t)(b * QL + q0 + 1) * DD + t] = o1 * inv1;
}

extern "C" void kernel_launch(void* const* d_in, const int* in_sizes, int n_in,
                              void* d_out, int out_size, void* d_ws, size_t ws_size,
                              hipStream_t stream) {
  const float* query     = (const float*)d_in[0];
  const float* key       = (const float*)d_in[1];
  const float* value     = (const float*)d_in[2];
  const int*   valid_len = (const int*)d_in[3];
  const float* Wq        = (const float*)d_in[4];
  const float* Wk        = (const float*)d_in[5];
  const float* v_w       = (const float*)d_in[6];
  float* out = (float*)d_out;

  float* qp  = (float*)d_ws;                        // B*QL*U floats (1 MB)
  float* kpT = qp + (size_t)Bsz * QL * UU;          // B*U*KL floats (4 MB)

  const int proj_blocks = (Bsz * QL + Bsz * KL) / PR;   // 1280
  proj_kernel<<<proj_blocks, 256, 0, stream>>>(query, key, Wq, Wk, valid_len,
                                               qp, kpT);

  const int fused_blocks = Bsz * (QL / FQB);            // 512
  fused_attn_kernel<<<fused_blocks, 256, 0, stream>>>(value, valid_len, v_w,
                                                      qp, kpT, out);
}

// Round 13
// 135.239 us; speedup vs baseline: 1.0405x; 1.0245x over previous
//
#include <hip/hip_runtime.h>
#include <hip/hip_bf16.h>

#ifndef __has_builtin
#define __has_builtin(x) 0
#endif

__device__ __forceinline__ float fast_exp2(float x) {
#if __has_builtin(__builtin_amdgcn_exp2f)
  return __builtin_amdgcn_exp2f(x);
#else
  return exp2f(x);
#endif
}
__device__ __forceinline__ float fast_rcp(float x) {
#if __has_builtin(__builtin_amdgcn_rcpf)
  return __builtin_amdgcn_rcpf(x);
#else
  return 1.0f / x;
#endif
}

constexpr int Bsz = 8, QL = 128, KL = 512, DD = 256, UU = 256;
constexpr int PR = 4;                    // rows per proj block (1280 blocks)
constexpr int DT = 8;                    // d-chunk in proj pipeline
constexpr int UH = 128;                  // u-half size in scores split
constexpr float NEG_INF = -1e6f;
constexpr float C2 = 2.885390081777927f; // 2*log2(e): exp2(C2*x) == exp(2x)

// ---------------------------------------------------------------------------
// Kernel 1: projections, pre-scaled by C2 (R8 config, ~20us attributed).
//   qp [b][q][u]  natural;  kpT[b][u][k] transposed (scores lanes map to k).
// PR=4 -> 1280 blocks (5/CU). Masked key blocks exit early.
// ---------------------------------------------------------------------------
__global__ __launch_bounds__(256) void proj_kernel(
    const float* __restrict__ query, const float* __restrict__ key,
    const float* __restrict__ Wq, const float* __restrict__ Wk,
    const int* __restrict__ valid_len,
    float* __restrict__ qp, float* __restrict__ kpT)
{
  const int u   = threadIdx.x;
  const int blk = blockIdx.x;
  constexpr int QBLKS = Bsz * QL / PR;   // 256
  const bool isQ = blk < QBLKS;
  const int  m0  = isQ ? blk * PR : (blk - QBLKS) * PR;

  int kb_ = 0, kk0 = 0;
  if (!isQ) {
    kb_ = m0 / KL; kk0 = m0 % KL;
    if (kk0 >= valid_len[kb_]) return;   // masked rows never read downstream
  }
  const float* __restrict__ in = isQ ? query : key;
  const float* __restrict__ W  = isQ ? Wq : Wk;
  const float* r0 = in + (size_t)m0 * DD;

  float acc[PR];
#pragma unroll
  for (int r = 0; r < PR; ++r) acc[r] = 0.f;

  float  w_c[DT], w_n[DT];
  float4 r_c[PR][2], r_n[PR][2];

#pragma unroll
  for (int j = 0; j < DT; ++j) w_c[j] = W[j * UU + u];
#pragma unroll
  for (int r = 0; r < PR; ++r) {
    r_c[r][0] = *reinterpret_cast<const float4*>(r0 + r * DD);
    r_c[r][1] = *reinterpret_cast<const float4*>(r0 + r * DD + 4);
  }

  for (int d = 0; d < DD; d += DT) {
    const int dn = (d + DT < DD) ? d + DT : 0;   // clamped dummy on last
#pragma unroll
    for (int j = 0; j < DT; ++j) w_n[j] = W[(dn + j) * UU + u];
#pragma unroll
    for (int r = 0; r < PR; ++r) {
      r_n[r][0] = *reinterpret_cast<const float4*>(r0 + r * DD + dn);
      r_n[r][1] = *reinterpret_cast<const float4*>(r0 + r * DD + dn + 4);
    }
#pragma unroll
    for (int r = 0; r < PR; ++r) {
      float a = acc[r];
      a = fmaf(r_c[r][0].x, w_c[0], a);
      a = fmaf(r_c[r][0].y, w_c[1], a);
      a = fmaf(r_c[r][0].z, w_c[2], a);
      a = fmaf(r_c[r][0].w, w_c[3], a);
      a = fmaf(r_c[r][1].x, w_c[4], a);
      a = fmaf(r_c[r][1].y, w_c[5], a);
      a = fmaf(r_c[r][1].z, w_c[6], a);
      a = fmaf(r_c[r][1].w, w_c[7], a);
      acc[r] = a;
    }
#pragma unroll
    for (int j = 0; j < DT; ++j) w_c[j] = w_n[j];
#pragma unroll
    for (int r = 0; r < PR; ++r) { r_c[r][0] = r_n[r][0]; r_c[r][1] = r_n[r][1]; }
  }

  if (isQ) {
    float* o = qp + (size_t)m0 * UU + u;
#pragma unroll
    for (int r = 0; r < PR; ++r) o[(size_t)r * UU] = acc[r] * C2;
  } else {
    float* o = kpT + ((size_t)kb_ * UU + u) * KL + kk0;
    *reinterpret_cast<float4*>(o) =
        make_float4(acc[0] * C2, acc[1] * C2, acc[2] * C2, acc[3] * C2);
  }
}

// ---------------------------------------------------------------------------
// Kernel 2: HALF-U scores partials. Block = (b, 2 q-rows, u-half).
// 1024 blocks x 4 waves = 4096 waves = 16/CU = 4/SIMD — 2x the TLP of every
// R8-R12 variant at FULL R9 per-lane ILP (4 accs, 8 trans/u). The u-split is
// what finally decouples wave count from ILP: scores are a sum over u, so
// two blocks each reduce half the u-range; partials summed in kernel 3.
// Each block is also half as long -> straggler tail halves.
//   scp[uh][b][q][k] = -sum_{u in half} 2*v_w[u]*rcp(1+exp2(qp+kp))
// Wave w owns k-strip [128w,128w+128); lane l owns k=128w+2l(+1).
// Fully-masked strips (128w >= vlen) skip; kernel 3 masks k >= vlen.
// ---------------------------------------------------------------------------
__global__ __launch_bounds__(256) void scores_half_kernel(
    const int* __restrict__ valid_len, const float* __restrict__ v_w,
    const float* __restrict__ qp, const float* __restrict__ kpT,
    float* __restrict__ scp)
{
  __shared__ __align__(16) float2 qpq_s[UH]; // 1 KB: (q0,q1) per u-in-half
  __shared__ __align__(16) float  w2_s[UH];  // 0.5 KB

  const int t   = threadIdx.x;
  const int blk = blockIdx.x;
  const int b   = blk & 7;                   // batch fastest: mixed vlen per CU
  const int qt  = (blk >> 3) & 63;           // 0..63
  const int uh  = blk >> 9;                  // 0..1
  const int q0  = qt * 2;
  const int u0  = uh * UH;
  const int vlen = valid_len[b];
  const int w = t >> 6, l = t & 63;

  // ---- stage qp rows (float2 per u) + 2*v_w for this u-half ----
  if (t < UH) {
    qpq_s[t] = make_float2(qp[(size_t)(b * QL + q0) * UU + u0 + t],
                           qp[(size_t)(b * QL + q0 + 1) * UU + u0 + t]);
  } else {
    const int i = t - UH;
    w2_s[i] = 2.0f * v_w[u0 + i];
  }
  __syncthreads();

  const int kb = 128 * w + 2 * l;            // lane's k pair base
  float a00 = 0.f, a01 = 0.f, a10 = 0.f, a11 = 0.f;  // [row][kslot]

  if (128 * w < vlen) {
    const float* __restrict__ kprow =
        kpT + (size_t)b * UU * KL + (size_t)u0 * KL + kb;
    float2 cur[8], nxt[8];
#pragma unroll
    for (int j = 0; j < 8; ++j)
      cur[j] = *reinterpret_cast<const float2*>(kprow + (size_t)j * KL);

    for (int ul = 0; ul < UH; ul += 8) {
      const int un = (ul + 8 < UH) ? ul + 8 : 0;   // clamped dummy on last
#pragma unroll
      for (int j = 0; j < 8; ++j)
        nxt[j] = *reinterpret_cast<const float2*>(kprow + (size_t)(un + j) * KL);
#pragma unroll
      for (int j = 0; j < 8; ++j) {
        const float2 qv = qpq_s[ul + j];     // ds_read_b64 broadcast
        const float  w2 = w2_s[ul + j];
        const float2 kv = cur[j];
        const float e00 = fast_exp2(qv.x + kv.x);
        const float e01 = fast_exp2(qv.x + kv.y);
        const float e10 = fast_exp2(qv.y + kv.x);
        const float e11 = fast_exp2(qv.y + kv.y);
        a00 = fmaf(w2, fast_rcp(1.0f + e00), a00);
        a01 = fmaf(w2, fast_rcp(1.0f + e01), a01);
        a10 = fmaf(w2, fast_rcp(1.0f + e10), a10);
        a11 = fmaf(w2, fast_rcp(1.0f + e11), a11);
      }
#pragma unroll
      for (int j = 0; j < 8; ++j) cur[j] = nxt[j];
    }
  }

  // write partials (coalesced float2 per row; k >= vlen lanes hold finite
  // garbage from ws-poison kpT — kernel 3 masks them before use)
  float* s0 = scp + (((size_t)uh * Bsz + b) * QL + q0) * KL + kb;
  *reinterpret_cast<float2*>(s0)      = make_float2(-a00, -a01);
  *reinterpret_cast<float2*>(s0 + KL) = make_float2(-a10, -a11);
}

// ---------------------------------------------------------------------------
// Kernel 3: sum partials + masked softmax + PV for one (b, q) row.
// 1024 blocks (4/CU), 256 threads. Thread t owns k = {2t,2t+1} for softmax;
// thread = d for PV (DD = 256). Weights unnormalized, final 1/sum scale.
// ---------------------------------------------------------------------------
__global__ __launch_bounds__(256) void softmax_pv_kernel(
    const float* __restrict__ value, const int* __restrict__ valid_len,
    const float* __restrict__ scp, float* __restrict__ out)
{
  __shared__ __align__(16) float sps[KL];    // 2 KB exp weights
  __shared__ float red_s[8];                 // [0..3] max, [4..7] sum

  const int t   = threadIdx.x;
  const int blk = blockIdx.x;
  const int b   = blk & 7;
  const int q   = blk >> 3;                  // 0..127
  const int vlen = valid_len[b];
  const int w = t >> 6, l = t & 63;

  // ---- sum the two u-half partials; mask k >= vlen ----
  const float2 p0 = *reinterpret_cast<const float2*>(
      scp + (((size_t)0 * Bsz + b) * QL + q) * KL + 2 * t);
  const float2 p1 = *reinterpret_cast<const float2*>(
      scp + (((size_t)1 * Bsz + b) * QL + q) * KL + 2 * t);
  const float s0 = (2 * t     < vlen) ? (p0.x + p1.x) : NEG_INF;
  const float s1 = (2 * t + 1 < vlen) ? (p0.y + p1.y) : NEG_INF;

  // ---- softmax over 512 k ----
  float m = fmaxf(s0, s1);
#pragma unroll
  for (int off = 32; off >= 1; off >>= 1) m = fmaxf(m, __shfl_xor(m, off, 64));
  if (l == 0) red_s[w] = m;
  __syncthreads();
  const float mr = fmaxf(fmaxf(red_s[0], red_s[1]), fmaxf(red_s[2], red_s[3]));
  const float e0 = __expf(s0 - mr);          // masked -> exp(-1e6) = 0
  const float e1 = __expf(s1 - mr);
  *reinterpret_cast<float2*>(&sps[2 * t]) = make_float2(e0, e1);
  float s = e0 + e1;
#pragma unroll
  for (int off = 32; off >= 1; off >>= 1) s += __shfl_xor(s, off, 64);
  if (l == 0) red_s[4 + w] = s;
  __syncthreads();
  const float inv =
      fast_rcp(red_s[4] + red_s[5] + red_s[6] + red_s[7]);  // sum >= 1

  // ---- PV: thread = d; unnormalized weights, final scale ----
  const float* __restrict__ vb = value + (size_t)b * KL * DD + t;
  float o0 = 0.f;
  const int kmax = (vlen + 15) & ~15;        // sps beyond vlen is exactly 0

  float vc[16], vn[16], p_r[16];
#pragma unroll
  for (int j = 0; j < 16; ++j) vc[j] = vb[(size_t)j * DD];
  for (int k = 0; k < kmax; k += 16) {
    const int kn = (k + 16 < kmax) ? k + 16 : 0;
#pragma unroll
    for (int i = 0; i < 4; ++i)
      *reinterpret_cast<float4*>(&p_r[4 * i]) =
          *reinterpret_cast<const float4*>(&sps[k + 4 * i]);
#pragma unroll
    for (int j = 0; j < 16; ++j) vn[j] = vb[(size_t)(kn + j) * DD];
#pragma unroll
    for (int j = 0; j < 16; ++j) o0 = fmaf(p_r[j], vc[j], o0);
#pragma unroll
    for (int j = 0; j < 16; ++j) vc[j] = vn[j];
  }
  out[(size_t)(b * QL + q) * DD + t] = o0 * inv;
}

extern "C" void kernel_launch(void* const* d_in, const int* in_sizes, int n_in,
                              void* d_out, int out_size, void* d_ws, size_t ws_size,
                              hipStream_t stream) {
  const float* query     = (const float*)d_in[0];
  const float* key       = (const float*)d_in[1];
  const float* value     = (const float*)d_in[2];
  const int*   valid_len = (const int*)d_in[3];
  const float* Wq        = (const float*)d_in[4];
  const float* Wk        = (const float*)d_in[5];
  const float* v_w       = (const float*)d_in[6];
  float* out = (float*)d_out;

  float* qp  = (float*)d_ws;                        // B*QL*U floats  (1 MB)
  float* kpT = qp + (size_t)Bsz * QL * UU;          // B*U*KL floats  (4 MB)
  float* scp = kpT + (size_t)Bsz * UU * KL;         // 2*B*QL*KL      (4 MB)

  const int proj_blocks = (Bsz * QL + Bsz * KL) / PR;   // 1280
  proj_kernel<<<proj_blocks, 256, 0, stream>>>(query, key, Wq, Wk, valid_len,
                                               qp, kpT);

  const int score_blocks = Bsz * (QL / 2) * 2;          // 1024
  scores_half_kernel<<<score_blocks, 256, 0, stream>>>(valid_len, v_w, qp,
                                                       kpT, scp);

  const int pv_blocks = Bsz * QL;                       // 1024
  softmax_pv_kernel<<<pv_blocks, 256, 0, stream>>>(value, valid_len, scp, out);
}